// Round 3
// baseline (385.197 us; speedup 1.0000x reference)
//
#include <hip/hip_runtime.h>

#define EPSILON 0.1f
#define F_IN 256
#define F_OUT 96
#define NF 3
#define TCOLS 288  // NF * F_OUT, t row layout: [n][ii*96 + f], bf16
#define LDA 40     // LDS leading dim (ushorts) for A tile
#define LDB 40

typedef __attribute__((ext_vector_type(8))) short bf8_t;   // 8 bf16 (4 VGPRs)
typedef __attribute__((ext_vector_type(4))) float f32x4;

__device__ inline ushort f2b(float f) {
    union { float f; unsigned u; } v; v.f = f;
    unsigned u = v.u;
    return (ushort)((u + 0x7FFFu + ((u >> 16) & 1u)) >> 16);  // RNE
}
__device__ inline float b2f(ushort h) {
    union { unsigned u; float f; } v; v.u = ((unsigned)h) << 16;
    return v.f;
}

// ---------------- histogram: edge counts per row (4 edges/thread) ----------------
__global__ void hist_kernel(const int* __restrict__ row, int* __restrict__ cnt, int E) {
    int i = (blockIdx.x * blockDim.x + threadIdx.x) * 4;
    if (i + 3 < E) {
        int4 r = *(const int4*)(row + i);
        atomicAdd(&cnt[r.x], 1);
        atomicAdd(&cnt[r.y], 1);
        atomicAdd(&cnt[r.z], 1);
        atomicAdd(&cnt[r.w], 1);
    } else {
        for (int j = i; j < E; ++j) atomicAdd(&cnt[row[j]], 1);
    }
}

// ---------------- scan step 1: per-block (1024 elems) sums ----------------
__global__ __launch_bounds__(256) void scan_part(const int* __restrict__ cnt,
                                                 int* __restrict__ bsums, int N) {
    int i = blockIdx.x * 1024 + threadIdx.x * 4;
    int v = 0;
    if (i + 3 < N) {
        int4 q = *(const int4*)(cnt + i);
        v = q.x + q.y + q.z + q.w;
    } else {
        for (int j = 0; j < 4; ++j)
            if (i + j < N) v += cnt[i + j];
    }
    #pragma unroll
    for (int d = 32; d > 0; d >>= 1) v += __shfl_xor(v, d, 64);
    __shared__ int wsum[4];
    int lane = threadIdx.x & 63, wid = threadIdx.x >> 6;
    if (lane == 0) wsum[wid] = v;
    __syncthreads();
    if (threadIdx.x == 0) bsums[blockIdx.x] = wsum[0] + wsum[1] + wsum[2] + wsum[3];
}

// ---------------- scan step 2: exclusive scan of block sums (<=64 blocks) ----------------
__global__ void scan_sums(int* __restrict__ bsums, int* __restrict__ row_ptr,
                          int nb, int E, int N) {
    int lane = threadIdx.x;
    int v = (lane < nb) ? bsums[lane] : 0;
    int s = v;
    #pragma unroll
    for (int d = 1; d < 64; d <<= 1) {
        int o = __shfl_up(s, d, 64);
        if (lane >= d) s += o;
    }
    if (lane < nb) bsums[lane] = s - v;  // exclusive
    if (lane == 0) row_ptr[N] = E;
}

// ---------------- scan step 3: full exclusive scan, write row_ptr + offs ----------------
__global__ __launch_bounds__(256) void scan_write(const int* __restrict__ cnt,
                                                  const int* __restrict__ bsums,
                                                  int* __restrict__ row_ptr,
                                                  int* __restrict__ offs, int N) {
    int i = blockIdx.x * 1024 + threadIdx.x * 4;
    int q0 = 0, q1 = 0, q2 = 0, q3 = 0;
    if (i + 3 < N) {
        int4 q = *(const int4*)(cnt + i);
        q0 = q.x; q1 = q.y; q2 = q.z; q3 = q.w;
    } else {
        if (i     < N) q0 = cnt[i];
        if (i + 1 < N) q1 = cnt[i + 1];
        if (i + 2 < N) q2 = cnt[i + 2];
        if (i + 3 < N) q3 = cnt[i + 3];
    }
    int tsum = q0 + q1 + q2 + q3;
    int lane = threadIdx.x & 63, wid = threadIdx.x >> 6;
    int s = tsum;
    #pragma unroll
    for (int d = 1; d < 64; d <<= 1) {
        int o = __shfl_up(s, d, 64);
        if (lane >= d) s += o;
    }
    __shared__ int wsum[4];
    if (lane == 63) wsum[wid] = s;
    __syncthreads();
    int woff = 0;
    for (int w = 0; w < wid; ++w) woff += wsum[w];
    int e0 = bsums[blockIdx.x] + woff + (s - tsum);
    if (i     < N) { row_ptr[i]     = e0; offs[i]     = e0; } e0 += q0;
    if (i + 1 < N) { row_ptr[i + 1] = e0; offs[i + 1] = e0; } e0 += q1;
    if (i + 2 < N) { row_ptr[i + 2] = e0; offs[i + 2] = e0; } e0 += q2;
    if (i + 3 < N) { row_ptr[i + 3] = e0; offs[i + 3] = e0; }
}

// ---------------- scatter edges into CSR order (packed 8B record) ----------------
__global__ void scatter_kernel(const int* __restrict__ row, const int* __restrict__ col,
                               const float* __restrict__ vals, int* __restrict__ offs,
                               int2* __restrict__ evs, int E) {
    int e = blockIdx.x * blockDim.x + threadIdx.x;
    if (e < E) {
        int r = row[e];
        int p = atomicAdd(&offs[r], 1);
        evs[p] = make_int2(col[e], __float_as_int(vals[e]));
    }
}

// ---------------- W convert+transpose: wt[gc][k] = bf16(w[ii][k][f]), gc = ii*96+f ----------------
__global__ void cvt_w(const float* __restrict__ w, ushort* __restrict__ wt) {
    int idx = blockIdx.x * 256 + threadIdx.x;   // < 288*256
    if (idx >= TCOLS * F_IN) return;
    int gc = idx >> 8;          // 0..287
    int k  = idx & 255;
    int ii = gc / F_OUT;
    int c  = gc - ii * F_OUT;
    wt[idx] = f2b(w[(size_t)ii * (F_IN * F_OUT) + (size_t)k * F_OUT + c]);
}

// ---------------- MFMA GEMM: t[n][288] = bf16( dsc[ii][n] * (x @ W[ii])[n][f] ) ----------------
__global__ __launch_bounds__(256) void gemm_mfma(const float* __restrict__ x,
                                                 const ushort* __restrict__ wt,
                                                 const float* __restrict__ dsc,
                                                 ushort* __restrict__ t, int N) {
    __shared__ ushort As[64 * LDA];
    __shared__ ushort Bs[TCOLS * LDB];

    int tid = threadIdx.x;
    int lane = tid & 63, wave = tid >> 6;
    int m0 = blockIdx.x * 64;

    f32x4 acc[18];
    #pragma unroll
    for (int j = 0; j < 18; ++j) acc[j] = (f32x4){0.f, 0.f, 0.f, 0.f};

    int arow = wave * 16 + (lane & 15);
    int koff = (lane >> 4) * 8;      // 0,8,16,24

    for (int k0 = 0; k0 < F_IN; k0 += 32) {
        // stage A: 64x32 fp32 -> bf16 LDS, 2 float4 per thread
        #pragma unroll
        for (int it = 0; it < 2; ++it) {
            int idx = tid + it * 256;         // 0..511
            int r = idx >> 3;                 // 0..63
            int kq = (idx & 7) * 4;           // 0..28
            float4 xv = make_float4(0.f, 0.f, 0.f, 0.f);
            if (m0 + r < N)
                xv = *(const float4*)(x + (size_t)(m0 + r) * F_IN + k0 + kq);
            ushort* d = As + r * LDA + kq;
            d[0] = f2b(xv.x); d[1] = f2b(xv.y); d[2] = f2b(xv.z); d[3] = f2b(xv.w);
        }
        // stage B: 288 x 32 bf16 (from wt[gc][k]), 16B chunks
        #pragma unroll
        for (int j = 0; j < 5; ++j) {
            int idx = tid + j * 256;          // 0..1279
            if (idx < TCOLS * 4) {
                int gc = idx >> 2;            // 0..287
                int ch = (idx & 3) * 8;       // ushort offset, 16B chunks
                *(uint4*)(Bs + gc * LDB + ch) =
                    *(const uint4*)(wt + (size_t)gc * F_IN + k0 + ch);
            }
        }
        __syncthreads();
        bf8_t a = *(const bf8_t*)(As + arow * LDA + koff);
        #pragma unroll
        for (int j = 0; j < 18; ++j) {
            bf8_t b = *(const bf8_t*)(Bs + (j * 16 + (lane & 15)) * LDB + koff);
            acc[j] = __builtin_amdgcn_mfma_f32_16x16x32_bf16(a, b, acc[j], 0, 0, 0);
        }
        __syncthreads();
    }

    // epilogue: C/D layout col=lane&15, row=(lane>>4)*4+reg
    int rowb = m0 + wave * 16 + (lane >> 4) * 4;
    float dscv[3][4];
    #pragma unroll
    for (int ii = 0; ii < 3; ++ii)
        #pragma unroll
        for (int r = 0; r < 4; ++r) {
            int row = rowb + r;
            dscv[ii][r] = (row < N) ? dsc[(size_t)ii * N + row] : 0.f;
        }
    #pragma unroll
    for (int j = 0; j < 18; ++j) {
        int gc = j * 16 + (lane & 15);
        int ii = j / 6;                       // 96 = 6 tiles of 16
        #pragma unroll
        for (int r = 0; r < 4; ++r) {
            int row = rowb + r;
            if (row < N)
                t[(size_t)row * TCOLS + gc] = f2b(dscv[ii][r] * acc[j][r]);
        }
    }
}

// ---------------- fused SpMM + diagonal + relu + D + bias ----------------
// one block per row; thread g in [0,288) owns global column g (= ii*96+f).
// One ushort gather per edge per thread, 4 edges in flight; LDS reduce over ii.
__global__ __launch_bounds__(320) void spmm_kernel(const ushort* __restrict__ t,
                                                   const int* __restrict__ row_ptr,
                                                   const int2* __restrict__ evs,
                                                   const int* __restrict__ cnt,
                                                   const float* __restrict__ dsc,
                                                   const float* __restrict__ bias,
                                                   float* __restrict__ out, int N) {
    __shared__ float red[TCOLS];
    int n = blockIdx.x;
    int g = threadIdx.x;
    int s = row_ptr[n], e = row_ptr[n + 1];

    if (g < TCOLS) {
        float a = 0.f;
        int p = s;
        for (; p + 3 < e; p += 4) {
            int2 q0 = evs[p];
            int2 q1 = evs[p + 1];
            int2 q2 = evs[p + 2];
            int2 q3 = evs[p + 3];
            ushort r0 = t[(size_t)q0.x * TCOLS + g];
            ushort r1 = t[(size_t)q1.x * TCOLS + g];
            ushort r2 = t[(size_t)q2.x * TCOLS + g];
            ushort r3 = t[(size_t)q3.x * TCOLS + g];
            a = fmaf(__int_as_float(q0.y), b2f(r0), a);
            a = fmaf(__int_as_float(q1.y), b2f(r1), a);
            a = fmaf(__int_as_float(q2.y), b2f(r2), a);
            a = fmaf(__int_as_float(q3.y), b2f(r3), a);
        }
        for (; p < e; ++p) {
            int2 q = evs[p];
            a = fmaf(__int_as_float(q.y), b2f(t[(size_t)q.x * TCOLS + g]), a);
        }
        int ii = g / F_OUT;
        float sign = (ii == 0) ? -1.f : 1.f;
        float epsdi = EPSILON / (float)(cnt[n] + 1);   // deg includes self loop
        float u = fmaf(sign * epsdi, b2f(t[(size_t)n * TCOLS + g]), a);
        red[g] = fmaxf(u, 0.f) * dsc[(size_t)ii * N + n];
    }
    __syncthreads();
    if (g < F_OUT) {
        out[(size_t)n * F_OUT + g] =
            red[g] + red[F_OUT + g] + red[2 * F_OUT + g] + bias[g];
    }
}

extern "C" void kernel_launch(void* const* d_in, const int* in_sizes, int n_in,
                              void* d_out, int out_size, void* d_ws, size_t ws_size,
                              hipStream_t stream) {
    const float* x    = (const float*)d_in[0];
    const float* adj  = (const float*)d_in[1];
    const float* dsc  = (const float*)d_in[2];
    const float* w    = (const float*)d_in[3];
    const float* bias = (const float*)d_in[4];
    const int*   ei   = (const int*)d_in[5];

    int E = in_sizes[1];
    int N = in_sizes[0] / F_IN;
    const int* row = ei;
    const int* col = ei + E;
    float* out = (float*)d_out;

    // workspace carve-up (256B aligned)
    char* p = (char*)d_ws;
    auto take = [&](size_t bytes) {
        char* r = p;
        p += (bytes + 255) & ~(size_t)255;
        return r;
    };
    int*    cnt     = (int*)take((size_t)N * 4);
    int*    row_ptr = (int*)take((size_t)(N + 1) * 4);
    int*    offs    = (int*)take((size_t)N * 4);
    int*    bsums   = (int*)take(64 * 4);
    int2*   evs     = (int2*)take((size_t)E * 8);
    ushort* wt      = (ushort*)take((size_t)TCOLS * F_IN * 2);
    ushort* t       = (ushort*)take((size_t)N * TCOLS * 2);   // 28.8 MB bf16

    hipMemsetAsync(cnt, 0, (size_t)N * 4, stream);
    cvt_w<<<(TCOLS * F_IN + 255) / 256, 256, 0, stream>>>(w, wt);
    hist_kernel<<<(E / 4 + 255) / 256, 256, 0, stream>>>(row, cnt, E);
    int nb = (N + 1023) / 1024;   // 49 <= 64
    scan_part<<<nb, 256, 0, stream>>>(cnt, bsums, N);
    scan_sums<<<1, 64, 0, stream>>>(bsums, row_ptr, nb, E, N);
    scan_write<<<nb, 256, 0, stream>>>(cnt, bsums, row_ptr, offs, N);
    scatter_kernel<<<(E + 255) / 256, 256, 0, stream>>>(row, col, adj, offs, evs, E);
    gemm_mfma<<<(N + 63) / 64, 256, 0, stream>>>(x, wt, dsc, t, N);
    spmm_kernel<<<N, 320, 0, stream>>>(t, row_ptr, evs, cnt, dsc, bias, out, N);
}

// Round 4
// 313.086 us; speedup vs baseline: 1.2303x; 1.2303x over previous
//
#include <hip/hip_runtime.h>

#define EPSILON 0.1f
#define F_IN 256
#define F_OUT 96
#define NF 3
#define TCOLS 288    // real columns: ii*96+f
#define TSTRIDE 320  // padded t row stride (bf16) = 640 B = 5 cache lines, line-aligned
#define LDA 40       // LDS leading dim (ushorts) for gemm A tile
#define LDB 40

typedef __attribute__((ext_vector_type(8))) short bf8_t;   // 8 bf16 (4 VGPRs)
typedef __attribute__((ext_vector_type(4))) float f32x4;

__device__ inline ushort f2b(float f) {
    union { float f; unsigned u; } v; v.f = f;
    unsigned u = v.u;
    return (ushort)((u + 0x7FFFu + ((u >> 16) & 1u)) >> 16);  // RNE
}
__device__ inline float blo(unsigned u) { return __uint_as_float(u << 16); }
__device__ inline float bhi(unsigned u) { return __uint_as_float(u & 0xffff0000u); }

// ---------------- histogram: edge counts per row (4 edges/thread) ----------------
__global__ void hist_kernel(const int* __restrict__ row, int* __restrict__ cnt, int E) {
    int i = (blockIdx.x * blockDim.x + threadIdx.x) * 4;
    if (i + 3 < E) {
        int4 r = *(const int4*)(row + i);
        atomicAdd(&cnt[r.x], 1);
        atomicAdd(&cnt[r.y], 1);
        atomicAdd(&cnt[r.z], 1);
        atomicAdd(&cnt[r.w], 1);
    } else {
        for (int j = i; j < E; ++j) atomicAdd(&cnt[row[j]], 1);
    }
}

// ---------------- scan step 1: per-block (1024 elems) sums ----------------
__global__ __launch_bounds__(256) void scan_part(const int* __restrict__ cnt,
                                                 int* __restrict__ bsums, int N) {
    int i = blockIdx.x * 1024 + threadIdx.x * 4;
    int v = 0;
    if (i + 3 < N) {
        int4 q = *(const int4*)(cnt + i);
        v = q.x + q.y + q.z + q.w;
    } else {
        for (int j = 0; j < 4; ++j)
            if (i + j < N) v += cnt[i + j];
    }
    #pragma unroll
    for (int d = 32; d > 0; d >>= 1) v += __shfl_xor(v, d, 64);
    __shared__ int wsum[4];
    int lane = threadIdx.x & 63, wid = threadIdx.x >> 6;
    if (lane == 0) wsum[wid] = v;
    __syncthreads();
    if (threadIdx.x == 0) bsums[blockIdx.x] = wsum[0] + wsum[1] + wsum[2] + wsum[3];
}

// ---------------- scan step 2: exclusive scan of block sums (<=64 blocks) ----------------
__global__ void scan_sums(int* __restrict__ bsums, int* __restrict__ row_ptr,
                          int nb, int E, int N) {
    int lane = threadIdx.x;
    int v = (lane < nb) ? bsums[lane] : 0;
    int s = v;
    #pragma unroll
    for (int d = 1; d < 64; d <<= 1) {
        int o = __shfl_up(s, d, 64);
        if (lane >= d) s += o;
    }
    if (lane < nb) bsums[lane] = s - v;  // exclusive
    if (lane == 0) row_ptr[N] = E;
}

// ---------------- scan step 3: full exclusive scan, write row_ptr + offs ----------------
__global__ __launch_bounds__(256) void scan_write(const int* __restrict__ cnt,
                                                  const int* __restrict__ bsums,
                                                  int* __restrict__ row_ptr,
                                                  int* __restrict__ offs, int N) {
    int i = blockIdx.x * 1024 + threadIdx.x * 4;
    int q0 = 0, q1 = 0, q2 = 0, q3 = 0;
    if (i + 3 < N) {
        int4 q = *(const int4*)(cnt + i);
        q0 = q.x; q1 = q.y; q2 = q.z; q3 = q.w;
    } else {
        if (i     < N) q0 = cnt[i];
        if (i + 1 < N) q1 = cnt[i + 1];
        if (i + 2 < N) q2 = cnt[i + 2];
        if (i + 3 < N) q3 = cnt[i + 3];
    }
    int tsum = q0 + q1 + q2 + q3;
    int lane = threadIdx.x & 63, wid = threadIdx.x >> 6;
    int s = tsum;
    #pragma unroll
    for (int d = 1; d < 64; d <<= 1) {
        int o = __shfl_up(s, d, 64);
        if (lane >= d) s += o;
    }
    __shared__ int wsum[4];
    if (lane == 63) wsum[wid] = s;
    __syncthreads();
    int woff = 0;
    for (int w = 0; w < wid; ++w) woff += wsum[w];
    int e0 = bsums[blockIdx.x] + woff + (s - tsum);
    if (i     < N) { row_ptr[i]     = e0; offs[i]     = e0; } e0 += q0;
    if (i + 1 < N) { row_ptr[i + 1] = e0; offs[i + 1] = e0; } e0 += q1;
    if (i + 2 < N) { row_ptr[i + 2] = e0; offs[i + 2] = e0; } e0 += q2;
    if (i + 3 < N) { row_ptr[i + 3] = e0; offs[i + 3] = e0; }
}

// ---------------- scatter edges into CSR order (packed 8B record) ----------------
__global__ void scatter_kernel(const int* __restrict__ row, const int* __restrict__ col,
                               const float* __restrict__ vals, int* __restrict__ offs,
                               int2* __restrict__ evs, int E) {
    int e = blockIdx.x * blockDim.x + threadIdx.x;
    if (e < E) {
        int r = row[e];
        int p = atomicAdd(&offs[r], 1);
        evs[p] = make_int2(col[e], __float_as_int(vals[e]));
    }
}

// ---------------- W convert+transpose: wt[gc][k] = bf16(w[ii][k][f]), gc = ii*96+f ----------------
__global__ void cvt_w(const float* __restrict__ w, ushort* __restrict__ wt) {
    int idx = blockIdx.x * 256 + threadIdx.x;   // < 288*256
    if (idx >= TCOLS * F_IN) return;
    int gc = idx >> 8;          // 0..287
    int k  = idx & 255;
    int ii = gc / F_OUT;
    int c  = gc - ii * F_OUT;
    wt[idx] = f2b(w[(size_t)ii * (F_IN * F_OUT) + (size_t)k * F_OUT + c]);
}

// ---------------- MFMA GEMM: t[n][g] = bf16( dsc[ii][n] * (x @ W[ii])[n][f] ) ----------------
__global__ __launch_bounds__(256) void gemm_mfma(const float* __restrict__ x,
                                                 const ushort* __restrict__ wt,
                                                 const float* __restrict__ dsc,
                                                 ushort* __restrict__ t, int N) {
    __shared__ ushort As[64 * LDA];
    __shared__ ushort Bs[TCOLS * LDB];

    int tid = threadIdx.x;
    int lane = tid & 63, wave = tid >> 6;
    int m0 = blockIdx.x * 64;

    f32x4 acc[18];
    #pragma unroll
    for (int j = 0; j < 18; ++j) acc[j] = (f32x4){0.f, 0.f, 0.f, 0.f};

    int arow = wave * 16 + (lane & 15);
    int koff = (lane >> 4) * 8;      // 0,8,16,24

    for (int k0 = 0; k0 < F_IN; k0 += 32) {
        // stage A: 64x32 fp32 -> bf16 LDS, 2 float4 per thread
        #pragma unroll
        for (int it = 0; it < 2; ++it) {
            int idx = tid + it * 256;         // 0..511
            int r = idx >> 3;                 // 0..63
            int kq = (idx & 7) * 4;           // 0..28
            float4 xv = make_float4(0.f, 0.f, 0.f, 0.f);
            if (m0 + r < N)
                xv = *(const float4*)(x + (size_t)(m0 + r) * F_IN + k0 + kq);
            ushort* d = As + r * LDA + kq;
            d[0] = f2b(xv.x); d[1] = f2b(xv.y); d[2] = f2b(xv.z); d[3] = f2b(xv.w);
        }
        // stage B: 288 x 32 bf16 (from wt[gc][k]), 16B chunks
        #pragma unroll
        for (int j = 0; j < 5; ++j) {
            int idx = tid + j * 256;          // 0..1279
            if (idx < TCOLS * 4) {
                int gc = idx >> 2;            // 0..287
                int ch = (idx & 3) * 8;       // ushort offset, 16B chunks
                *(uint4*)(Bs + gc * LDB + ch) =
                    *(const uint4*)(wt + (size_t)gc * F_IN + k0 + ch);
            }
        }
        __syncthreads();
        bf8_t a = *(const bf8_t*)(As + arow * LDA + koff);
        #pragma unroll
        for (int j = 0; j < 18; ++j) {
            bf8_t b = *(const bf8_t*)(Bs + (j * 16 + (lane & 15)) * LDB + koff);
            acc[j] = __builtin_amdgcn_mfma_f32_16x16x32_bf16(a, b, acc[j], 0, 0, 0);
        }
        __syncthreads();
    }

    // epilogue: C/D layout col=lane&15, row=(lane>>4)*4+reg
    int rowb = m0 + wave * 16 + (lane >> 4) * 4;
    float dscv[3][4];
    #pragma unroll
    for (int ii = 0; ii < 3; ++ii)
        #pragma unroll
        for (int r = 0; r < 4; ++r) {
            int row = rowb + r;
            dscv[ii][r] = (row < N) ? dsc[(size_t)ii * N + row] : 0.f;
        }
    #pragma unroll
    for (int j = 0; j < 18; ++j) {
        int gc = j * 16 + (lane & 15);
        int ii = j / 6;                       // 96 = 6 tiles of 16
        #pragma unroll
        for (int r = 0; r < 4; ++r) {
            int row = rowb + r;
            if (row < N)
                t[(size_t)row * TSTRIDE + gc] = f2b(dscv[ii][r] * acc[j][r]);
        }
    }
}

// ---------------- fused SpMM + diagonal + relu + D + bias ----------------
// wave-per-row, 4 rows/block. Lane l<40 owns uint4 chunk [8l,8l+8) of the padded
// 320-col t row. Edge records preloaded per 64-edge batch, distributed by readlane.
__device__ inline void acc8(float* acc, uint4 a, float v) {
    acc[0] = fmaf(v, blo(a.x), acc[0]); acc[1] = fmaf(v, bhi(a.x), acc[1]);
    acc[2] = fmaf(v, blo(a.y), acc[2]); acc[3] = fmaf(v, bhi(a.y), acc[3]);
    acc[4] = fmaf(v, blo(a.z), acc[4]); acc[5] = fmaf(v, bhi(a.z), acc[5]);
    acc[6] = fmaf(v, blo(a.w), acc[6]); acc[7] = fmaf(v, bhi(a.w), acc[7]);
}

__global__ __launch_bounds__(256) void spmm_kernel(const ushort* __restrict__ t,
                                                   const int* __restrict__ row_ptr,
                                                   const int2* __restrict__ evs,
                                                   const int* __restrict__ cnt,
                                                   const float* __restrict__ dsc,
                                                   const float* __restrict__ bias,
                                                   float* __restrict__ out, int N) {
    int lane = threadIdx.x & 63;
    int wave = threadIdx.x >> 6;
    int n = blockIdx.x * 4 + wave;
    if (n >= N) return;

    int s = row_ptr[n], e = row_ptr[n + 1];
    int coff = (lane < 40) ? lane * 8 : 0;   // ushort offset of this lane's chunk

    float acc[8];
    #pragma unroll
    for (int j = 0; j < 8; ++j) acc[j] = 0.f;

    for (int base = s; base < e; base += 64) {
        int idx = base + lane;
        int2 q = make_int2(0, 0);
        if (idx < e) q = evs[idx];
        int m = min(64, e - base);
        int j = 0;
        for (; j + 3 < m; j += 4) {
            int c0 = __shfl(q.x, j, 64);
            int c1 = __shfl(q.x, j + 1, 64);
            int c2 = __shfl(q.x, j + 2, 64);
            int c3 = __shfl(q.x, j + 3, 64);
            float v0 = __int_as_float(__shfl(q.y, j, 64));
            float v1 = __int_as_float(__shfl(q.y, j + 1, 64));
            float v2 = __int_as_float(__shfl(q.y, j + 2, 64));
            float v3 = __int_as_float(__shfl(q.y, j + 3, 64));
            uint4 a0 = *(const uint4*)(t + (size_t)c0 * TSTRIDE + coff);
            uint4 a1 = *(const uint4*)(t + (size_t)c1 * TSTRIDE + coff);
            uint4 a2 = *(const uint4*)(t + (size_t)c2 * TSTRIDE + coff);
            uint4 a3 = *(const uint4*)(t + (size_t)c3 * TSTRIDE + coff);
            acc8(acc, a0, v0);
            acc8(acc, a1, v1);
            acc8(acc, a2, v2);
            acc8(acc, a3, v3);
        }
        for (; j < m; ++j) {
            int c = __shfl(q.x, j, 64);
            float v = __int_as_float(__shfl(q.y, j, 64));
            uint4 a = *(const uint4*)(t + (size_t)c * TSTRIDE + coff);
            acc8(acc, a, v);
        }
    }

    // self term + relu + D scale (per-lane filter ii = lane/12 for lane<36)
    float sign = (lane < 12) ? -1.f : 1.f;
    float epsdi = EPSILON / (float)(cnt[n] + 1);   // deg includes self loop
    int ii = lane / 12;
    float dscv = (lane < 36) ? dsc[(size_t)ii * N + n] : 0.f;
    uint4 sv = *(const uint4*)(t + (size_t)n * TSTRIDE + coff);
    float se = sign * epsdi;
    float val[8];
    {
        unsigned u;
        u = sv.x; val[0] = fmaf(se, blo(u), acc[0]); val[1] = fmaf(se, bhi(u), acc[1]);
        u = sv.y; val[2] = fmaf(se, blo(u), acc[2]); val[3] = fmaf(se, bhi(u), acc[3]);
        u = sv.z; val[4] = fmaf(se, blo(u), acc[4]); val[5] = fmaf(se, bhi(u), acc[5]);
        u = sv.w; val[6] = fmaf(se, blo(u), acc[6]); val[7] = fmaf(se, bhi(u), acc[7]);
    }
    #pragma unroll
    for (int j = 0; j < 8; ++j) val[j] = fmaxf(val[j], 0.f) * dscv;

    // cross-filter reduce: out[8a+j] = val[a][j] + val[a+12][j] + val[a+24][j]
    float res[8];
    #pragma unroll
    for (int j = 0; j < 8; ++j) {
        float r1 = __shfl(val[j], lane + 12, 64);
        float r2 = __shfl(val[j], lane + 24, 64);
        res[j] = val[j] + r1 + r2;
    }
    if (lane < 12) {
        float4 b0 = *(const float4*)(bias + lane * 8);
        float4 b1 = *(const float4*)(bias + lane * 8 + 4);
        float4 o0 = make_float4(res[0] + b0.x, res[1] + b0.y, res[2] + b0.z, res[3] + b0.w);
        float4 o1 = make_float4(res[4] + b1.x, res[5] + b1.y, res[6] + b1.z, res[7] + b1.w);
        *(float4*)(out + (size_t)n * F_OUT + lane * 8) = o0;
        *(float4*)(out + (size_t)n * F_OUT + lane * 8 + 4) = o1;
    }
}

extern "C" void kernel_launch(void* const* d_in, const int* in_sizes, int n_in,
                              void* d_out, int out_size, void* d_ws, size_t ws_size,
                              hipStream_t stream) {
    const float* x    = (const float*)d_in[0];
    const float* adj  = (const float*)d_in[1];
    const float* dsc  = (const float*)d_in[2];
    const float* w    = (const float*)d_in[3];
    const float* bias = (const float*)d_in[4];
    const int*   ei   = (const int*)d_in[5];

    int E = in_sizes[1];
    int N = in_sizes[0] / F_IN;
    const int* row = ei;
    const int* col = ei + E;
    float* out = (float*)d_out;

    // workspace carve-up (256B aligned)
    char* p = (char*)d_ws;
    auto take = [&](size_t bytes) {
        char* r = p;
        p += (bytes + 255) & ~(size_t)255;
        return r;
    };
    int*    cnt     = (int*)take((size_t)N * 4);
    int*    row_ptr = (int*)take((size_t)(N + 1) * 4);
    int*    offs    = (int*)take((size_t)N * 4);
    int*    bsums   = (int*)take(64 * 4);
    int2*   evs     = (int2*)take((size_t)E * 8);
    ushort* wt      = (ushort*)take((size_t)TCOLS * F_IN * 2);
    ushort* t       = (ushort*)take(((size_t)N * TSTRIDE + 256) * 2);  // 32 MB bf16, padded

    hipMemsetAsync(cnt, 0, (size_t)N * 4, stream);
    cvt_w<<<(TCOLS * F_IN + 255) / 256, 256, 0, stream>>>(w, wt);
    hist_kernel<<<(E / 4 + 255) / 256, 256, 0, stream>>>(row, cnt, E);
    int nb = (N + 1023) / 1024;   // 49 <= 64
    scan_part<<<nb, 256, 0, stream>>>(cnt, bsums, N);
    scan_sums<<<1, 64, 0, stream>>>(bsums, row_ptr, nb, E, N);
    scan_write<<<nb, 256, 0, stream>>>(cnt, bsums, row_ptr, offs, N);
    scatter_kernel<<<(E + 255) / 256, 256, 0, stream>>>(row, col, adj, offs, evs, E);
    gemm_mfma<<<(N + 63) / 64, 256, 0, stream>>>(x, wt, dsc, t, N);
    spmm_kernel<<<(N + 3) / 4, 256, 0, stream>>>(t, row_ptr, evs, cnt, dsc, bias, out, N);
}